// Round 7
// baseline (10018.351 us; speedup 1.0000x reference)
//
#include <hip/hip_runtime.h>

// ---------------- constants ----------------
#define NS   256   // batch
#define NB   128   // blocks: 2 samples per block
#define TS   64    // time steps
#define DS   32
#define DA   8
#define DD   512   // model dim
#define HH   8     // heads
#define HD   64    // head dim
#define FF   2048
#define INP  40    // DS+DA
#define INPP 20    // packed pairs of input
#define INPG 24    // padded to 3 groups
#define DP   256   // packed pairs of D
#define KVKP 276   // pairs of kv input (552/2)
#define KVKPP 280  // padded to 35 groups
#define KVO  1032
#define FFP  1024  // packed pairs of FF

// packed-weight ws offsets (uint elements, after 128-uint header)
// layout: [KPpad/8][Dout][8]  (8 consecutive k-pairs per column contiguous)
#define OFF_ODE 0
#define SZ_ODE  (32*512*8)
#define OFF_KV  (OFF_ODE+SZ_ODE)
#define SZ_KV   (35*1032*8)
#define OFF_IN  (OFF_KV+SZ_KV)
#define SZ_IN   (3*512*8)
#define OFF_Q   (OFF_IN+SZ_IN)
#define SZ_Q    (32*512*8)
#define OFF_OUT (OFF_Q+SZ_Q)
#define SZ_OUT  (32*512*8)
#define OFF_F1  (OFF_OUT+SZ_OUT)
#define SZ_F1   (32*2048*8)
#define OFF_F2  (OFF_F1+SZ_F1)
#define SZ_F2   (128*512*8)
#define OFF_DEC (OFF_F2+SZ_F2)
#define SZ_DEC  (32*32*8)

#define DEV __device__ __forceinline__

typedef _Float16 half2_t __attribute__((ext_vector_type(2)));

DEV half2_t as_h2(unsigned int u) { return __builtin_bit_cast(half2_t, u); }

DEV float dot2f(unsigned int w, unsigned int x, float acc) {
#if __has_builtin(__builtin_amdgcn_fdot2)
  return __builtin_amdgcn_fdot2(as_h2(w), as_h2(x), acc, false);
#else
  half2_t a = as_h2(w), b = as_h2(x);
  return acc + (float)a[0] * (float)b[0] + (float)a[1] * (float)b[1];
#endif
}

DEV unsigned int pack2f(float a, float b) {
  unsigned short ua = __builtin_bit_cast(unsigned short, (_Float16)a);
  unsigned short ub = __builtin_bit_cast(unsigned short, (_Float16)b);
  return ((unsigned int)ub << 16) | (unsigned int)ua;
}

DEV float fast_tanh(float x) {
  float ax = fabsf(x);
  float e  = __expf(-2.0f * ax);
  float r  = (1.0f - e) / (1.0f + e);
  return copysignf(r, x);
}

DEV float fast_sigmoid(float x) { return 1.0f / (1.0f + __expf(-x)); }

#define LD4(p) (*reinterpret_cast<const uint4*>(p))

// dual-sample grouped packed matvec: weights loaded once, dotted against two x vectors
DEV void dotG2(const unsigned int* __restrict__ Wc, int strideG,
               const unsigned int* __restrict__ xa, const unsigned int* __restrict__ xb,
               int NG, float inita, float initb, float& outa, float& outb) {
  float a0 = inita, a1 = 0.f, a2 = 0.f, a3 = 0.f;
  float b0 = initb, b1 = 0.f, b2 = 0.f, b3 = 0.f;
  #pragma unroll 4
  for (int g = 0; g < NG; ++g) {
    uint4 w0 = LD4(Wc + g * strideG);
    uint4 w1 = LD4(Wc + g * strideG + 4);
    uint4 xa0 = LD4(xa + g * 8);
    uint4 xa1 = LD4(xa + g * 8 + 4);
    uint4 xb0 = LD4(xb + g * 8);
    uint4 xb1 = LD4(xb + g * 8 + 4);
    a0 = dot2f(w0.x, xa0.x, a0); a1 = dot2f(w0.y, xa0.y, a1);
    a2 = dot2f(w0.z, xa0.z, a2); a3 = dot2f(w0.w, xa0.w, a3);
    a0 = dot2f(w1.x, xa1.x, a0); a1 = dot2f(w1.y, xa1.y, a1);
    a2 = dot2f(w1.z, xa1.z, a2); a3 = dot2f(w1.w, xa1.w, a3);
    b0 = dot2f(w0.x, xb0.x, b0); b1 = dot2f(w0.y, xb0.y, b1);
    b2 = dot2f(w0.z, xb0.z, b2); b3 = dot2f(w0.w, xb0.w, b3);
    b0 = dot2f(w1.x, xb1.x, b0); b1 = dot2f(w1.y, xb1.y, b1);
    b2 = dot2f(w1.z, xb1.z, b2); b3 = dot2f(w1.w, xb1.w, b3);
  }
  outa = (a0 + a1) + (a2 + a3);
  outb = (b0 + b1) + (b2 + b3);
}

// ---------------- weight f32 -> grouped packed f16 pairs ----------------
// src: [K][Dout] f32 (row-major).  dst: [KPpad/8][Dout][8] packed pairs.
__global__ void pack_wg_kernel(const float* __restrict__ src, unsigned int* __restrict__ dst,
                               int K, int KPpad, int Dout) {
  int idx = blockIdx.x * blockDim.x + threadIdx.x;
  int total = KPpad * Dout;
  if (idx >= total) return;
  int kp = idx / Dout;
  int j  = idx - kp * Dout;
  int r0 = 2 * kp, r1 = r0 + 1;
  float lo = (r0 < K) ? src[r0 * Dout + j] : 0.f;
  float hi = (r1 < K) ? src[r1 * Dout + j] : 0.f;
  int kg = kp >> 3, sub = kp & 7;
  dst[((kg * Dout + j) << 3) + sub] = pack2f(lo, hi);
}

// ---------------- main persistent 2-samples-per-block kernel ----------------
__global__ __launch_bounds__(512, 2) void fwp_main(
    const float* __restrict__ states, const float* __restrict__ actions,
    const float* __restrict__ tsteps,
    const float* __restrict__ b_ode, const float* __restrict__ b_in,
    const float* __restrict__ ln_in_g, const float* __restrict__ ln_in_b,
    const float* __restrict__ b_q, const float* __restrict__ b_kv,
    const float* __restrict__ b_out,
    const float* __restrict__ ln_ff_g, const float* __restrict__ ln_ff_b,
    const float* __restrict__ b_ff1, const float* __restrict__ b_ff2,
    const float* __restrict__ b_dec,
    const unsigned int* __restrict__ Wode, const unsigned int* __restrict__ Wkv,
    const unsigned int* __restrict__ Win,  const unsigned int* __restrict__ Wq,
    const unsigned int* __restrict__ Wout, const unsigned int* __restrict__ Wff1,
    const unsigned int* __restrict__ Wff2, const unsigned int* __restrict__ Wdec,
    unsigned int* __restrict__ ctrs, float* __restrict__ outp) {

  const int b = blockIdx.x, tid = threadIdx.x;
  const int w = tid >> 6, lane = tid & 63;
  const int n0 = 2 * b;

  __shared__ alignas(16) float        sh_h[2][DD];
  __shared__ alignas(16) unsigned int sh_hp[2][DP];
  __shared__ alignas(16) unsigned int sh_xp[2][KVKPP];
  __shared__ alignas(16) unsigned int sh_dp[2][INPG];
  __shared__ alignas(16) float        sh_t[2][DD];
  __shared__ alignas(16) unsigned int sh_p[2][DP];
  __shared__ alignas(16) float        sh_kvb[2][KVO];
  __shared__ alignas(16) float        sh_k[2][DD];
  __shared__ alignas(16) float        sh_v[2][DD];
  __shared__ alignas(16) float        sh_q[2][DD];
  __shared__ float                    sh_lr[2][HH];
  __shared__ alignas(16) float        sh_ff[2][FF];
  __shared__ alignas(16) unsigned int sh_ffp[2][FFP];
  __shared__ float                    sh_red[2][16];
  __shared__ alignas(16) float        sh_decp[2][512];
  __shared__ int                      sh_flag;

  float W2A[64], W2B[64];
  #pragma unroll
  for (int i = 0; i < 64; ++i) { W2A[i] = 0.f; W2B[i] = 0.f; }

  sh_h[0][tid] = 0.f; sh_h[1][tid] = 0.f;
  if (tid < DP) { sh_hp[0][tid] = 0u; sh_hp[1][tid] = 0u; }
  if (tid < (KVKPP - KVKP)) { sh_xp[0][KVKP + tid] = 0u; sh_xp[1][KVKP + tid] = 0u; }
  if (tid < (INPG - INPP))  { sh_dp[0][INPP + tid] = 0u; sh_dp[1][INPP + tid] = 0u; }

  bool pace = true;
  unsigned int* ctr = ctrs + 16 * (b & 7);   // one counter per XCD group (16 blocks each)

  for (int t = 0; t < TS; ++t) {
    __syncthreads();

    // ---- loose pacing barrier (bounded spin; perf-only, deadlock-free)
    if (pace) {
      if (tid == 0) {
        sh_flag = 0;
        __hip_atomic_fetch_add(ctr, 1u, __ATOMIC_RELAXED, __HIP_MEMORY_SCOPE_AGENT);
        unsigned int tgt = 16u * (unsigned int)(t + 1);
        int it = 0;
        while (__hip_atomic_load(ctr, __ATOMIC_RELAXED, __HIP_MEMORY_SCOPE_AGENT) < tgt) {
          if (++it > 4096) { sh_flag = 1; break; }
          __builtin_amdgcn_s_sleep(8);
        }
      }
      __syncthreads();
      if (sh_flag) pace = false;
    }

    // ---- load data (two samples; waves 0/1 in parallel) & dts
    if (w < 2 && lane < INPP) {
      int n = n0 + w;
      int i0 = 2 * lane, i1 = i0 + 1;
      float a = (i0 < DS) ? states[(n * TS + t) * DS + i0] : actions[(n * TS + t) * DA + (i0 - DS)];
      float c = (i1 < DS) ? states[(n * TS + t) * DS + i1] : actions[(n * TS + t) * DA + (i1 - DS)];
      unsigned int p = pack2f(a, c);
      sh_xp[w][lane] = p;
      sh_dp[w][lane] = p;
    }
    const float sdtA = 0.25f * (tsteps[n0 * (TS + 1) + t + 1] - tsteps[n0 * (TS + 1) + t]);
    const float sdtB = 0.25f * (tsteps[(n0 + 1) * (TS + 1) + t + 1] - tsteps[(n0 + 1) * (TS + 1) + t]);

    // ---- ODE: 4 Euler steps, h += sdt * tanh(h @ W_ode + b_ode)
    for (int e = 0; e < 4; ++e) {
      float accA, accB;
      float bo = b_ode[tid];
      dotG2(Wode + tid * 8, DD * 8, sh_hp[0], sh_hp[1], 32, bo, bo, accA, accB);
      sh_h[0][tid] += sdtA * fast_tanh(accA);
      sh_h[1][tid] += sdtB * fast_tanh(accB);
      __syncthreads();
      if (tid < DP) {
        sh_hp[0][tid] = pack2f(sh_h[0][2 * tid], sh_h[0][2 * tid + 1]);
        sh_hp[1][tid] = pack2f(sh_h[1][2 * tid], sh_h[1][2 * tid + 1]);
      }
      __syncthreads();
    }

    // ---- x = [data, h1] packed
    if (tid < DP) {
      sh_xp[0][INPP + tid] = sh_hp[0][tid];
      sh_xp[1][INPP + tid] = sh_hp[1][tid];
    }
    __syncthreads();

    // ---- kv = x @ W_kv + b_kv   (1032 cols)
    for (int j = tid; j < KVO; j += 512) {
      float ra, rb, bk = b_kv[j];
      dotG2(Wkv + j * 8, KVO * 8, sh_xp[0], sh_xp[1], 35, bk, bk, ra, rb);
      sh_kvb[0][j] = ra; sh_kvb[1][j] = rb;
    }
    __syncthreads();

    // ---- k = softmax(head), v = tanh, lr = sigmoid  (both samples)
    #pragma unroll
    for (int s = 0; s < 2; ++s) {
      float kx = sh_kvb[s][tid];
      float km = kx;
      #pragma unroll
      for (int o = 32; o; o >>= 1) km = fmaxf(km, __shfl_xor(km, o));
      float ke = __expf(kx - km);
      float ks = ke;
      #pragma unroll
      for (int o = 32; o; o >>= 1) ks += __shfl_xor(ks, o);
      sh_k[s][tid] = ke / ks;
      sh_v[s][tid] = fast_tanh(sh_kvb[s][DD + tid]);
      if (tid < HH) sh_lr[s][tid] = fast_sigmoid(sh_kvb[s][2 * DD + tid]);
    }

    // ---- q path: LN(data@W_in + b_in) @ W_q + b_q, softmax per head
    float y1A, y1B;
    {
      float bi = b_in[tid];
      dotG2(Win + tid * 8, DD * 8, sh_dp[0], sh_dp[1], 3, bi, bi, y1A, y1B);
      float s1A = y1A, s2A = y1A * y1A, s1B = y1B, s2B = y1B * y1B;
      #pragma unroll
      for (int o = 32; o; o >>= 1) {
        s1A += __shfl_xor(s1A, o); s2A += __shfl_xor(s2A, o);
        s1B += __shfl_xor(s1B, o); s2B += __shfl_xor(s2B, o);
      }
      if (lane == 0) {
        sh_red[0][2 * w] = s1A; sh_red[0][2 * w + 1] = s2A;
        sh_red[1][2 * w] = s1B; sh_red[1][2 * w + 1] = s2B;
      }
      __syncthreads();
      float t1A = 0.f, t2A = 0.f, t1B = 0.f, t2B = 0.f;
      #pragma unroll
      for (int i = 0; i < 8; ++i) {
        t1A += sh_red[0][2 * i]; t2A += sh_red[0][2 * i + 1];
        t1B += sh_red[1][2 * i]; t2B += sh_red[1][2 * i + 1];
      }
      float mA = t1A * (1.0f / DD), mB = t1B * (1.0f / DD);
      float vA = fmaxf(t2A * (1.0f / DD) - mA * mA, 0.f);
      float vB = fmaxf(t2B * (1.0f / DD) - mB * mB, 0.f);
      float rA = rsqrtf(vA + 1e-5f), rB = rsqrtf(vB + 1e-5f);
      float g = ln_in_g[tid], bb = ln_in_b[tid];
      sh_t[0][tid] = (y1A - mA) * rA * g + bb;
      sh_t[1][tid] = (y1B - mB) * rB * g + bb;
    }
    __syncthreads();
    if (tid < DP) {
      sh_p[0][tid] = pack2f(sh_t[0][2 * tid], sh_t[0][2 * tid + 1]);
      sh_p[1][tid] = pack2f(sh_t[1][2 * tid], sh_t[1][2 * tid + 1]);
    }
    __syncthreads();
    {
      float qA, qB, bq = b_q[tid];
      dotG2(Wq + tid * 8, DD * 8, sh_p[0], sh_p[1], 32, bq, bq, qA, qB);
      float mA = qA, mB = qB;
      #pragma unroll
      for (int o = 32; o; o >>= 1) { mA = fmaxf(mA, __shfl_xor(mA, o)); mB = fmaxf(mB, __shfl_xor(mB, o)); }
      float eA = __expf(qA - mA), eB = __expf(qB - mB);
      float sA = eA, sB = eB;
      #pragma unroll
      for (int o = 32; o; o >>= 1) { sA += __shfl_xor(sA, o); sB += __shfl_xor(sB, o); }
      sh_q[0][tid] = eA / sA;
      sh_q[1][tid] = eB / sB;
    }
    __syncthreads();

    // ---- fused fast-weight update + query (W2 rows in registers, both samples)
    {
      float lvA = sh_lr[0][w] * sh_v[0][tid];
      float lvB = sh_lr[1][w] * sh_v[1][tid];
      float accA = 0.f, accB = 0.f;
      const float* kbA = sh_k[0] + w * HD;
      const float* qbA = sh_q[0] + w * HD;
      const float* kbB = sh_k[1] + w * HD;
      const float* qbB = sh_q[1] + w * HD;
      #pragma unroll
      for (int jc = 0; jc < 16; ++jc) {
        float4 kA = *reinterpret_cast<const float4*>(kbA + 4 * jc);
        float4 qA = *reinterpret_cast<const float4*>(qbA + 4 * jc);
        float4 kB = *reinterpret_cast<const float4*>(kbB + 4 * jc);
        float4 qB = *reinterpret_cast<const float4*>(qbB + 4 * jc);
        W2A[4 * jc + 0] += lvA * kA.x; accA += W2A[4 * jc + 0] * qA.x;
        W2A[4 * jc + 1] += lvA * kA.y; accA += W2A[4 * jc + 1] * qA.y;
        W2A[4 * jc + 2] += lvA * kA.z; accA += W2A[4 * jc + 2] * qA.z;
        W2A[4 * jc + 3] += lvA * kA.w; accA += W2A[4 * jc + 3] * qA.w;
        W2B[4 * jc + 0] += lvB * kB.x; accB += W2B[4 * jc + 0] * qB.x;
        W2B[4 * jc + 1] += lvB * kB.y; accB += W2B[4 * jc + 1] * qB.y;
        W2B[4 * jc + 2] += lvB * kB.z; accB += W2B[4 * jc + 2] * qB.z;
        W2B[4 * jc + 3] += lvB * kB.w; accB += W2B[4 * jc + 3] * qB.w;
      }
      sh_t[0][tid] = accA;
      sh_t[1][tid] = accB;
    }
    __syncthreads();
    if (tid < DP) {
      sh_p[0][tid] = pack2f(sh_t[0][2 * tid], sh_t[0][2 * tid + 1]);
      sh_p[1][tid] = pack2f(sh_t[1][2 * tid], sh_t[1][2 * tid + 1]);
    }
    __syncthreads();

    // ---- out1 = out @ W_out + b_out
    float o1A, o1B;
    {
      float bo = b_out[tid];
      dotG2(Wout + tid * 8, DD * 8, sh_p[0], sh_p[1], 32, bo, bo, o1A, o1B);
    }

    // ---- LN_ff
    {
      float s1A = o1A, s2A = o1A * o1A, s1B = o1B, s2B = o1B * o1B;
      #pragma unroll
      for (int o = 32; o; o >>= 1) {
        s1A += __shfl_xor(s1A, o); s2A += __shfl_xor(s2A, o);
        s1B += __shfl_xor(s1B, o); s2B += __shfl_xor(s2B, o);
      }
      if (lane == 0) {
        sh_red[0][2 * w] = s1A; sh_red[0][2 * w + 1] = s2A;
        sh_red[1][2 * w] = s1B; sh_red[1][2 * w + 1] = s2B;
      }
      __syncthreads();
      float t1A = 0.f, t2A = 0.f, t1B = 0.f, t2B = 0.f;
      #pragma unroll
      for (int i = 0; i < 8; ++i) {
        t1A += sh_red[0][2 * i]; t2A += sh_red[0][2 * i + 1];
        t1B += sh_red[1][2 * i]; t2B += sh_red[1][2 * i + 1];
      }
      float mA = t1A * (1.0f / DD), mB = t1B * (1.0f / DD);
      float vA = fmaxf(t2A * (1.0f / DD) - mA * mA, 0.f);
      float vB = fmaxf(t2B * (1.0f / DD) - mB * mB, 0.f);
      float rA = rsqrtf(vA + 1e-5f), rB = rsqrtf(vB + 1e-5f);
      float g = ln_ff_g[tid], bb = ln_ff_b[tid];
      sh_t[0][tid] = (o1A - mA) * rA * g + bb;
      sh_t[1][tid] = (o1B - mB) * rB * g + bb;
    }
    __syncthreads();
    if (tid < DP) {
      sh_p[0][tid] = pack2f(sh_t[0][2 * tid], sh_t[0][2 * tid + 1]);
      sh_p[1][tid] = pack2f(sh_t[1][2 * tid], sh_t[1][2 * tid + 1]);
    }
    __syncthreads();

    // ---- FF1 + relu (2048 cols; two passes of 2 cols x 2 samples)
    #pragma unroll
    for (int pass = 0; pass < 2; ++pass) {
      int c0 = tid + pass * 1024;
      int c1 = c0 + 512;
      float fA0 = b_ff1[c0], fA1 = b_ff1[c1];
      float fB0 = fA0, fB1 = fA1;
      #pragma unroll 2
      for (int g = 0; g < 32; ++g) {
        const unsigned int* wb = Wff1 + g * (FF * 8) + c0 * 8;
        uint4 w00 = LD4(wb);
        uint4 w01 = LD4(wb + 4);
        uint4 w10 = LD4(wb + 512 * 8);
        uint4 w11 = LD4(wb + 512 * 8 + 4);
        uint4 xA0 = LD4(sh_p[0] + g * 8);
        uint4 xA1 = LD4(sh_p[0] + g * 8 + 4);
        uint4 xB0 = LD4(sh_p[1] + g * 8);
        uint4 xB1 = LD4(sh_p[1] + g * 8 + 4);
        fA0 = dot2f(w00.x, xA0.x, fA0); fA0 = dot2f(w00.y, xA0.y, fA0);
        fA0 = dot2f(w00.z, xA0.z, fA0); fA0 = dot2f(w00.w, xA0.w, fA0);
        fA0 = dot2f(w01.x, xA1.x, fA0); fA0 = dot2f(w01.y, xA1.y, fA0);
        fA0 = dot2f(w01.z, xA1.z, fA0); fA0 = dot2f(w01.w, xA1.w, fA0);
        fA1 = dot2f(w10.x, xA0.x, fA1); fA1 = dot2f(w10.y, xA0.y, fA1);
        fA1 = dot2f(w10.z, xA0.z, fA1); fA1 = dot2f(w10.w, xA0.w, fA1);
        fA1 = dot2f(w11.x, xA1.x, fA1); fA1 = dot2f(w11.y, xA1.y, fA1);
        fA1 = dot2f(w11.z, xA1.z, fA1); fA1 = dot2f(w11.w, xA1.w, fA1);
        fB0 = dot2f(w00.x, xB0.x, fB0); fB0 = dot2f(w00.y, xB0.y, fB0);
        fB0 = dot2f(w00.z, xB0.z, fB0); fB0 = dot2f(w00.w, xB0.w, fB0);
        fB0 = dot2f(w01.x, xB1.x, fB0); fB0 = dot2f(w01.y, xB1.y, fB0);
        fB0 = dot2f(w01.z, xB1.z, fB0); fB0 = dot2f(w01.w, xB1.w, fB0);
        fB1 = dot2f(w10.x, xB0.x, fB1); fB1 = dot2f(w10.y, xB0.y, fB1);
        fB1 = dot2f(w10.z, xB0.z, fB1); fB1 = dot2f(w10.w, xB0.w, fB1);
        fB1 = dot2f(w11.x, xB1.x, fB1); fB1 = dot2f(w11.y, xB1.y, fB1);
        fB1 = dot2f(w11.z, xB1.z, fB1); fB1 = dot2f(w11.w, xB1.w, fB1);
      }
      sh_ff[0][c0] = fmaxf(fA0, 0.f);
      sh_ff[0][c1] = fmaxf(fA1, 0.f);
      sh_ff[1][c0] = fmaxf(fB0, 0.f);
      sh_ff[1][c1] = fmaxf(fB1, 0.f);
    }
    __syncthreads();
    sh_ffp[0][tid]       = pack2f(sh_ff[0][2 * tid], sh_ff[0][2 * tid + 1]);
    sh_ffp[0][tid + 512] = pack2f(sh_ff[0][1024 + 2 * tid], sh_ff[0][1025 + 2 * tid]);
    sh_ffp[1][tid]       = pack2f(sh_ff[1][2 * tid], sh_ff[1][2 * tid + 1]);
    sh_ffp[1][tid + 512] = pack2f(sh_ff[1][1024 + 2 * tid], sh_ff[1][1025 + 2 * tid]);
    __syncthreads();

    // ---- FF2 + bias + residual -> new h1 (carry)
    {
      float o2A, o2B, bf = b_ff2[tid];
      dotG2(Wff2 + tid * 8, DD * 8, sh_ffp[0], sh_ffp[1], 128, bf, bf, o2A, o2B);
      sh_h[0][tid] = o2A + o1A;
      sh_h[1][tid] = o2B + o1B;
    }
    __syncthreads();
    if (tid < DP) {
      sh_hp[0][tid] = pack2f(sh_h[0][2 * tid], sh_h[0][2 * tid + 1]);
      sh_hp[1][tid] = pack2f(sh_h[1][2 * tid], sh_h[1][2 * tid + 1]);
    }
    __syncthreads();

    // ---- decoder: pred = out @ W_dec + b_dec   (32 cols, 16 k-chunks of 2 groups)
    {
      int col = tid & 31, ch = tid >> 5;
      const unsigned int* wbse = Wdec + col * 8;
      float aA = 0.f, aB = 0.f;
      #pragma unroll
      for (int g = 2 * ch; g < 2 * ch + 2; ++g) {
        uint4 w0 = LD4(wbse + g * (DS * 8));
        uint4 w1 = LD4(wbse + g * (DS * 8) + 4);
        uint4 xA0 = LD4(sh_hp[0] + g * 8);
        uint4 xA1 = LD4(sh_hp[0] + g * 8 + 4);
        uint4 xB0 = LD4(sh_hp[1] + g * 8);
        uint4 xB1 = LD4(sh_hp[1] + g * 8 + 4);
        aA = dot2f(w0.x, xA0.x, aA); aA = dot2f(w0.y, xA0.y, aA);
        aA = dot2f(w0.z, xA0.z, aA); aA = dot2f(w0.w, xA0.w, aA);
        aA = dot2f(w1.x, xA1.x, aA); aA = dot2f(w1.y, xA1.y, aA);
        aA = dot2f(w1.z, xA1.z, aA); aA = dot2f(w1.w, xA1.w, aA);
        aB = dot2f(w0.x, xB0.x, aB); aB = dot2f(w0.y, xB0.y, aB);
        aB = dot2f(w0.z, xB0.z, aB); aB = dot2f(w0.w, xB0.w, aB);
        aB = dot2f(w1.x, xB1.x, aB); aB = dot2f(w1.y, xB1.y, aB);
        aB = dot2f(w1.z, xB1.z, aB); aB = dot2f(w1.w, xB1.w, aB);
      }
      sh_decp[0][tid] = aA;
      sh_decp[1][tid] = aB;
    }
    __syncthreads();
    if (w < 2 && lane < DS) {
      float s = b_dec[lane];
      #pragma unroll
      for (int c = 0; c < 16; ++c) s += sh_decp[w][c * 32 + lane];
      outp[((n0 + w) * TS + t) * DS + lane] = s;
    }
  }
}

// ---------------- host launcher ----------------
extern "C" void kernel_launch(void* const* d_in, const int* in_sizes, int n_in,
                              void* d_out, int out_size, void* d_ws, size_t ws_size,
                              hipStream_t stream) {
  (void)in_sizes; (void)n_in; (void)out_size; (void)ws_size;

  const float* states   = (const float*)d_in[0];
  const float* actions  = (const float*)d_in[1];
  const float* tsteps   = (const float*)d_in[2];
  const float* W_ode    = (const float*)d_in[3];
  const float* b_ode    = (const float*)d_in[4];
  const float* W_in     = (const float*)d_in[5];
  const float* b_in     = (const float*)d_in[6];
  const float* ln_in_g  = (const float*)d_in[7];
  const float* ln_in_b  = (const float*)d_in[8];
  const float* W_q      = (const float*)d_in[9];
  const float* b_q      = (const float*)d_in[10];
  const float* W_kv     = (const float*)d_in[11];
  const float* b_kv     = (const float*)d_in[12];
  const float* W_out    = (const float*)d_in[13];
  const float* b_out    = (const float*)d_in[14];
  const float* ln_ff_g  = (const float*)d_in[15];
  const float* ln_ff_b  = (const float*)d_in[16];
  const float* W_ff1    = (const float*)d_in[17];
  const float* b_ff1    = (const float*)d_in[18];
  const float* W_ff2    = (const float*)d_in[19];
  const float* b_ff2    = (const float*)d_in[20];
  const float* W_dec    = (const float*)d_in[21];
  const float* b_dec    = (const float*)d_in[22];

  unsigned int* wsbase = (unsigned int*)d_ws;
  unsigned int* ctrs   = wsbase;           // 8 counters, 64B apart (512B region)
  unsigned int* W      = wsbase + 128;     // packed weights

  hipMemsetAsync(d_ws, 0, 512, stream);

  auto launch_pack = [&](const float* src, unsigned int* dst, int K, int KPpad, int Dout) {
    int total = KPpad * Dout;
    int blocks = (total + 255) / 256;
    pack_wg_kernel<<<blocks, 256, 0, stream>>>(src, dst, K, KPpad, Dout);
  };

  launch_pack(W_ode, W + OFF_ODE, 512,  256, 512);
  launch_pack(W_kv,  W + OFF_KV,  552,  280, 1032);
  launch_pack(W_in,  W + OFF_IN,  40,   24,  512);
  launch_pack(W_q,   W + OFF_Q,   512,  256, 512);
  launch_pack(W_out, W + OFF_OUT, 512,  256, 512);
  launch_pack(W_ff1, W + OFF_F1,  512,  256, 2048);
  launch_pack(W_ff2, W + OFF_F2,  2048, 1024, 512);
  launch_pack(W_dec, W + OFF_DEC, 512,  256, 32);

  fwp_main<<<NB, 512, 0, stream>>>(
      states, actions, tsteps,
      b_ode, b_in, ln_in_g, ln_in_b, b_q, b_kv, b_out, ln_ff_g, ln_ff_b,
      b_ff1, b_ff2, b_dec,
      W + OFF_ODE, W + OFF_KV, W + OFF_IN, W + OFF_Q,
      W + OFF_OUT, W + OFF_F1, W + OFF_F2, W + OFF_DEC,
      ctrs, (float*)d_out);
}

// Round 8
// 6664.991 us; speedup vs baseline: 1.5031x; 1.5031x over previous
//
#include <hip/hip_runtime.h>

// ---------------- constants ----------------
#define NS   256   // batch = blocks (1 sample per block)
#define TS   64
#define DS   32
#define DA   8
#define DD   512
#define HH   8
#define HD   64
#define FF   2048
#define INP  40
#define INPP 20
#define INPG 24
#define DP   256
#define KVKP 276
#define KVKPP 280
#define KVO  1032
#define FFP  1024

// packed-weight ws offsets (uint elements, after 128-uint header)
// layout: [KPpad/8][Dout][8]
#define OFF_ODE 0
#define SZ_ODE  (32*512*8)
#define OFF_KV  (OFF_ODE+SZ_ODE)
#define SZ_KV   (35*1032*8)
#define OFF_IN  (OFF_KV+SZ_KV)
#define SZ_IN   (3*512*8)
#define OFF_Q   (OFF_IN+SZ_IN)
#define SZ_Q    (32*512*8)
#define OFF_OUT (OFF_Q+SZ_Q)
#define SZ_OUT  (32*512*8)
#define OFF_F1  (OFF_OUT+SZ_OUT)
#define SZ_F1   (32*2048*8)
#define OFF_F2  (OFF_F1+SZ_F1)
#define SZ_F2   (128*512*8)
#define OFF_DEC (OFF_F2+SZ_F2)
#define SZ_DEC  (32*32*8)

#define DEV __device__ __forceinline__

typedef _Float16 half2_t __attribute__((ext_vector_type(2)));

DEV half2_t as_h2(unsigned int u) { return __builtin_bit_cast(half2_t, u); }

DEV float dot2f(unsigned int w, unsigned int x, float acc) {
#if __has_builtin(__builtin_amdgcn_fdot2)
  return __builtin_amdgcn_fdot2(as_h2(w), as_h2(x), acc, false);
#else
  half2_t a = as_h2(w), b = as_h2(x);
  return acc + (float)a[0] * (float)b[0] + (float)a[1] * (float)b[1];
#endif
}

DEV unsigned int pack2f(float a, float b) {
  unsigned short ua = __builtin_bit_cast(unsigned short, (_Float16)a);
  unsigned short ub = __builtin_bit_cast(unsigned short, (_Float16)b);
  return ((unsigned int)ub << 16) | (unsigned int)ua;
}

DEV float fast_tanh(float x) {
  float ax = fabsf(x);
  float e  = __expf(-2.0f * ax);
  float r  = (1.0f - e) / (1.0f + e);
  return copysignf(r, x);
}

DEV float fast_sigmoid(float x) { return 1.0f / (1.0f + __expf(-x)); }

#define LD4(p) (*reinterpret_cast<const uint4*>(p))

// grouped packed matvec column dot (one sample)
DEV float dotG(const unsigned int* __restrict__ Wc, int strideG,
               const unsigned int* __restrict__ xq, int NG, float init) {
  float a0 = init, a1 = 0.f, a2 = 0.f, a3 = 0.f;
  #pragma unroll 4
  for (int g = 0; g < NG; ++g) {
    uint4 w0 = LD4(Wc + g * strideG);
    uint4 w1 = LD4(Wc + g * strideG + 4);
    uint4 x0 = LD4(xq + g * 8);
    uint4 x1 = LD4(xq + g * 8 + 4);
    a0 = dot2f(w0.x, x0.x, a0); a1 = dot2f(w0.y, x0.y, a1);
    a2 = dot2f(w0.z, x0.z, a2); a3 = dot2f(w0.w, x0.w, a3);
    a0 = dot2f(w1.x, x1.x, a0); a1 = dot2f(w1.y, x1.y, a1);
    a2 = dot2f(w1.z, x1.z, a2); a3 = dot2f(w1.w, x1.w, a3);
  }
  return (a0 + a1) + (a2 + a3);
}

// ---------------- weight f32 -> grouped packed f16 pairs ----------------
__global__ void pack_wg_kernel(const float* __restrict__ src, unsigned int* __restrict__ dst,
                               int K, int KPpad, int Dout) {
  int idx = blockIdx.x * blockDim.x + threadIdx.x;
  int total = KPpad * Dout;
  if (idx >= total) return;
  int kp = idx / Dout;
  int j  = idx - kp * Dout;
  int r0 = 2 * kp, r1 = r0 + 1;
  float lo = (r0 < K) ? src[r0 * Dout + j] : 0.f;
  float hi = (r1 < K) ? src[r1 * Dout + j] : 0.f;
  int kg = kp >> 3, sub = kp & 7;
  dst[((kg * Dout + j) << 3) + sub] = pack2f(lo, hi);
}

// ---------------- main: 1 sample/block, 1024 threads (16 waves), K-split ----------------
__global__ __launch_bounds__(1024, 4) void fwp_main(
    const float* __restrict__ states, const float* __restrict__ actions,
    const float* __restrict__ tsteps,
    const float* __restrict__ b_ode, const float* __restrict__ b_in,
    const float* __restrict__ ln_in_g, const float* __restrict__ ln_in_b,
    const float* __restrict__ b_q, const float* __restrict__ b_kv,
    const float* __restrict__ b_out,
    const float* __restrict__ ln_ff_g, const float* __restrict__ ln_ff_b,
    const float* __restrict__ b_ff1, const float* __restrict__ b_ff2,
    const float* __restrict__ b_dec,
    const unsigned int* __restrict__ Wode, const unsigned int* __restrict__ Wkv,
    const unsigned int* __restrict__ Win,  const unsigned int* __restrict__ Wq,
    const unsigned int* __restrict__ Wout, const unsigned int* __restrict__ Wff1,
    const unsigned int* __restrict__ Wff2, const unsigned int* __restrict__ Wdec,
    unsigned int* __restrict__ ctrs, float* __restrict__ outp) {

  const int n = blockIdx.x, tid = threadIdx.x;
  const int w = tid >> 6, lane = tid & 63;
  const int col = tid & 511;          // column for 512-wide matvecs
  const int sub = tid >> 9;           // K-split half: 0 or 1
  const int strideG = DD * 8;

  __shared__ alignas(16) float        sh_h[DD];
  __shared__ alignas(16) unsigned int sh_hp[DP];
  __shared__ alignas(16) unsigned int sh_xp[KVKPP];
  __shared__ alignas(16) unsigned int sh_dp[INPG];
  __shared__ alignas(16) float        sh_t[DD];
  __shared__ alignas(16) unsigned int sh_p[DP];
  __shared__ alignas(16) float        sh_kvb[KVO];
  __shared__ alignas(16) float        sh_k[DD];
  __shared__ alignas(16) float        sh_v[DD];
  __shared__ alignas(16) float        sh_q[DD];
  __shared__ float                    sh_lr[HH];
  __shared__ alignas(16) float        sh_ff[FF];
  __shared__ alignas(16) unsigned int sh_ffp[FFP];
  __shared__ float                    sh_red[16];
  __shared__ alignas(16) float        sh_decp[1024];
  __shared__ alignas(16) float        sh_part[512];
  __shared__ int                      sh_flag;

  // W2 fast weights: head = w>>1, row = lane, k-half = (w&1)*32 -> 32 regs/thread
  float W2r[32];
  #pragma unroll
  for (int i = 0; i < 32; ++i) W2r[i] = 0.f;

  if (tid < DD) sh_h[tid] = 0.f;
  if (tid < DP) sh_hp[tid] = 0u;
  if (tid < (KVKPP - KVKP)) sh_xp[KVKP + tid] = 0u;
  if (tid < (INPG - INPP))  sh_dp[INPP + tid] = 0u;

  bool pace = true;
  unsigned int* ctr = ctrs + 16 * (n & 7);   // per-XCD-group counter (32 blocks/group)

  for (int t = 0; t < TS; ++t) {
    __syncthreads();

    // ---- loose pacing barrier (bounded spin; perf-only, deadlock-free)
    if (pace) {
      if (tid == 0) {
        sh_flag = 0;
        __hip_atomic_fetch_add(ctr, 1u, __ATOMIC_RELAXED, __HIP_MEMORY_SCOPE_AGENT);
        unsigned int tgt = 32u * (unsigned int)(t + 1);
        int it = 0;
        while (__hip_atomic_load(ctr, __ATOMIC_RELAXED, __HIP_MEMORY_SCOPE_AGENT) < tgt) {
          if (++it > 4096) { sh_flag = 1; break; }
          __builtin_amdgcn_s_sleep(8);
        }
      }
      __syncthreads();
      if (sh_flag) pace = false;
    }

    // ---- load data (40 inputs -> 20 packed pairs)
    if (tid < INPP) {
      int i0 = 2 * tid, i1 = i0 + 1;
      float a = (i0 < DS) ? states[(n * TS + t) * DS + i0] : actions[(n * TS + t) * DA + (i0 - DS)];
      float c = (i1 < DS) ? states[(n * TS + t) * DS + i1] : actions[(n * TS + t) * DA + (i1 - DS)];
      unsigned int p = pack2f(a, c);
      sh_xp[tid] = p;
      sh_dp[tid] = p;
    }
    const float sdt = 0.25f * (tsteps[n * (TS + 1) + t + 1] - tsteps[n * (TS + 1) + t]);

    // ---- ODE: 4 Euler steps; K split across halves (16 groups each)
    for (int e = 0; e < 4; ++e) {
      float acc = dotG(Wode + col * 8 + sub * 16 * strideG, strideG,
                       sh_hp + sub * 128, 16, sub ? 0.f : b_ode[col]);
      if (sub) sh_part[col] = acc;
      __syncthreads();
      if (!sub) sh_h[tid] += sdt * fast_tanh(acc + sh_part[tid]);
      __syncthreads();
      if (tid < DP) sh_hp[tid] = pack2f(sh_h[2 * tid], sh_h[2 * tid + 1]);
      __syncthreads();
    }

    // ---- x = [data, h1]
    if (tid < DP) sh_xp[INPP + tid] = sh_hp[tid];
    __syncthreads();

    // ---- kv = x @ W_kv + b_kv (1032 cols, full-K per thread)
    for (int j = tid; j < KVO; j += 1024)
      sh_kvb[j] = dotG(Wkv + j * 8, KVO * 8, sh_xp, 35, b_kv[j]);
    __syncthreads();

    // ---- k = softmax(head), v = tanh, lr = sigmoid (waves 0-7)
    if (tid < DD) {
      float kx = sh_kvb[tid];
      float km = kx;
      #pragma unroll
      for (int o = 32; o; o >>= 1) km = fmaxf(km, __shfl_xor(km, o));
      float ke = __expf(kx - km);
      float ks = ke;
      #pragma unroll
      for (int o = 32; o; o >>= 1) ks += __shfl_xor(ks, o);
      sh_k[tid] = ke / ks;
      sh_v[tid] = fast_tanh(sh_kvb[DD + tid]);
    }
    if (tid < HH) sh_lr[tid] = fast_sigmoid(sh_kvb[2 * DD + tid]);

    // ---- q path: LN(data@W_in + b_in) @ W_q + b_q, softmax per head
    {
      float y1 = 0.f;
      if (tid < DD) y1 = dotG(Win + tid * 8, strideG, sh_dp, 3, b_in[tid]);
      float s1 = y1, s2 = y1 * y1;
      #pragma unroll
      for (int o = 32; o; o >>= 1) { s1 += __shfl_xor(s1, o); s2 += __shfl_xor(s2, o); }
      if (tid < DD && lane == 0) { sh_red[2 * w] = s1; sh_red[2 * w + 1] = s2; }
      __syncthreads();
      if (tid < DD) {
        float t1 = 0.f, t2 = 0.f;
        #pragma unroll
        for (int i = 0; i < 8; ++i) { t1 += sh_red[2 * i]; t2 += sh_red[2 * i + 1]; }
        float m  = t1 * (1.0f / DD);
        float va = fmaxf(t2 * (1.0f / DD) - m * m, 0.f);
        float rs = rsqrtf(va + 1e-5f);
        sh_t[tid] = (y1 - m) * rs * ln_in_g[tid] + ln_in_b[tid];
      }
    }
    __syncthreads();
    if (tid < DP) sh_p[tid] = pack2f(sh_t[2 * tid], sh_t[2 * tid + 1]);
    __syncthreads();
    {
      float qacc = dotG(Wq + col * 8 + sub * 16 * strideG, strideG,
                        sh_p + sub * 128, 16, sub ? 0.f : b_q[col]);
      if (sub) sh_part[col] = qacc;
      __syncthreads();
      if (!sub) {
        float qt = qacc + sh_part[tid];
        float qm = qt;
        #pragma unroll
        for (int o = 32; o; o >>= 1) qm = fmaxf(qm, __shfl_xor(qm, o));
        float qe = __expf(qt - qm);
        float qs = qe;
        #pragma unroll
        for (int o = 32; o; o >>= 1) qs += __shfl_xor(qs, o);
        sh_q[tid] = qe / qs;
      }
    }
    __syncthreads();

    // ---- fused fast-weight update + query (wave pair per head, 32 k each)
    {
      int hh = w >> 1, kh = (w & 1) << 5;
      float lv = sh_lr[hh] * sh_v[(hh << 6) + lane];
      float acc = 0.f;
      const float* kb = sh_k + (hh << 6) + kh;
      const float* qb = sh_q + (hh << 6) + kh;
      #pragma unroll
      for (int jc = 0; jc < 8; ++jc) {
        float4 k4 = *reinterpret_cast<const float4*>(kb + 4 * jc);
        float4 q4 = *reinterpret_cast<const float4*>(qb + 4 * jc);
        W2r[4 * jc + 0] += lv * k4.x; acc += W2r[4 * jc + 0] * q4.x;
        W2r[4 * jc + 1] += lv * k4.y; acc += W2r[4 * jc + 1] * q4.y;
        W2r[4 * jc + 2] += lv * k4.z; acc += W2r[4 * jc + 2] * q4.z;
        W2r[4 * jc + 3] += lv * k4.w; acc += W2r[4 * jc + 3] * q4.w;
      }
      if (!(w & 1)) sh_part[(hh << 6) + lane] = acc;
      __syncthreads();
      if (w & 1) sh_t[(hh << 6) + lane] = acc + sh_part[(hh << 6) + lane];
    }
    __syncthreads();
    if (tid < DP) sh_p[tid] = pack2f(sh_t[2 * tid], sh_t[2 * tid + 1]);
    __syncthreads();

    // ---- out1 = out @ W_out + b_out (K-split)
    float o1 = 0.f;
    {
      float oacc = dotG(Wout + col * 8 + sub * 16 * strideG, strideG,
                        sh_p + sub * 128, 16, sub ? 0.f : b_out[col]);
      if (sub) sh_part[col] = oacc;
      __syncthreads();
      if (!sub) o1 = oacc + sh_part[tid];
    }

    // ---- LN_ff (threads 0-511 hold o1)
    {
      float s1 = o1, s2 = o1 * o1;
      #pragma unroll
      for (int o = 32; o; o >>= 1) { s1 += __shfl_xor(s1, o); s2 += __shfl_xor(s2, o); }
      if (tid < DD && lane == 0) { sh_red[2 * w] = s1; sh_red[2 * w + 1] = s2; }
      __syncthreads();
      if (tid < DD) {
        float t1 = 0.f, t2 = 0.f;
        #pragma unroll
        for (int i = 0; i < 8; ++i) { t1 += sh_red[2 * i]; t2 += sh_red[2 * i + 1]; }
        float m  = t1 * (1.0f / DD);
        float va = fmaxf(t2 * (1.0f / DD) - m * m, 0.f);
        float rs = rsqrtf(va + 1e-5f);
        sh_t[tid] = (o1 - m) * rs * ln_ff_g[tid] + ln_ff_b[tid];
      }
    }
    __syncthreads();
    if (tid < DP) sh_p[tid] = pack2f(sh_t[2 * tid], sh_t[2 * tid + 1]);
    __syncthreads();

    // ---- FF1 + relu (2048 cols, 2 per thread, full K)
    {
      float f0 = b_ff1[tid], f1 = b_ff1[tid + 1024];
      #pragma unroll 2
      for (int g = 0; g < 32; ++g) {
        const unsigned int* wb = Wff1 + g * (FF * 8) + tid * 8;
        uint4 w00 = LD4(wb);
        uint4 w01 = LD4(wb + 4);
        uint4 w10 = LD4(wb + 1024 * 8);
        uint4 w11 = LD4(wb + 1024 * 8 + 4);
        uint4 x0 = LD4(sh_p + g * 8);
        uint4 x1 = LD4(sh_p + g * 8 + 4);
        f0 = dot2f(w00.x, x0.x, f0); f0 = dot2f(w00.y, x0.y, f0);
        f0 = dot2f(w00.z, x0.z, f0); f0 = dot2f(w00.w, x0.w, f0);
        f0 = dot2f(w01.x, x1.x, f0); f0 = dot2f(w01.y, x1.y, f0);
        f0 = dot2f(w01.z, x1.z, f0); f0 = dot2f(w01.w, x1.w, f0);
        f1 = dot2f(w10.x, x0.x, f1); f1 = dot2f(w10.y, x0.y, f1);
        f1 = dot2f(w10.z, x0.z, f1); f1 = dot2f(w10.w, x0.w, f1);
        f1 = dot2f(w11.x, x1.x, f1); f1 = dot2f(w11.y, x1.y, f1);
        f1 = dot2f(w11.z, x1.z, f1); f1 = dot2f(w11.w, x1.w, f1);
      }
      sh_ff[tid]        = fmaxf(f0, 0.f);
      sh_ff[tid + 1024] = fmaxf(f1, 0.f);
    }
    __syncthreads();
    sh_ffp[tid] = pack2f(sh_ff[2 * tid], sh_ff[2 * tid + 1]);
    __syncthreads();

    // ---- FF2 + bias + residual -> new h1 (K=2048, split 64 groups per half)
    {
      float oacc = dotG(Wff2 + col * 8 + sub * 64 * strideG, strideG,
                        sh_ffp + sub * 512, 64, sub ? 0.f : b_ff2[col]);
      if (sub) sh_part[col] = oacc;
      __syncthreads();
      if (!sub) sh_h[tid] = oacc + sh_part[tid] + o1;
    }
    __syncthreads();
    if (tid < DP) sh_hp[tid] = pack2f(sh_h[2 * tid], sh_h[2 * tid + 1]);
    __syncthreads();

    // ---- decoder (32 cols x 32 k-chunks, 1 group each)
    {
      int colD = tid & 31, ch = tid >> 5;
      const unsigned int* wb = Wdec + colD * 8 + ch * (DS * 8);
      uint4 w0 = LD4(wb);
      uint4 w1 = LD4(wb + 4);
      uint4 x0 = LD4(sh_hp + ch * 8);
      uint4 x1 = LD4(sh_hp + ch * 8 + 4);
      float a = 0.f;
      a = dot2f(w0.x, x0.x, a); a = dot2f(w0.y, x0.y, a);
      a = dot2f(w0.z, x0.z, a); a = dot2f(w0.w, x0.w, a);
      a = dot2f(w1.x, x1.x, a); a = dot2f(w1.y, x1.y, a);
      a = dot2f(w1.z, x1.z, a); a = dot2f(w1.w, x1.w, a);
      sh_decp[tid] = a;
    }
    __syncthreads();
    if (tid < DS) {
      float s = b_dec[tid];
      #pragma unroll
      for (int c = 0; c < 32; ++c) s += sh_decp[c * 32 + tid];
      outp[(n * TS + t) * DS + tid] = s;
    }
  }
}

// ---------------- host launcher ----------------
extern "C" void kernel_launch(void* const* d_in, const int* in_sizes, int n_in,
                              void* d_out, int out_size, void* d_ws, size_t ws_size,
                              hipStream_t stream) {
  (void)in_sizes; (void)n_in; (void)out_size; (void)ws_size;

  const float* states   = (const float*)d_in[0];
  const float* actions  = (const float*)d_in[1];
  const float* tsteps   = (const float*)d_in[2];
  const float* W_ode    = (const float*)d_in[3];
  const float* b_ode    = (const float*)d_in[4];
  const float* W_in     = (const float*)d_in[5];
  const float* b_in     = (const float*)d_in[6];
  const float* ln_in_g  = (const float*)d_in[7];
  const float* ln_in_b  = (const float*)d_in[8];
  const float* W_q      = (const float*)d_in[9];
  const float* b_q      = (const float*)d_in[10];
  const float* W_kv     = (const float*)d_in[11];
  const float* b_kv     = (const float*)d_in[12];
  const float* W_out    = (const float*)d_in[13];
  const float* b_out    = (const float*)d_in[14];
  const float* ln_ff_g  = (const float*)d_in[15];
  const float* ln_ff_b  = (const float*)d_in[16];
  const float* W_ff1    = (const float*)d_in[17];
  const float* b_ff1    = (const float*)d_in[18];
  const float* W_ff2    = (const float*)d_in[19];
  const float* b_ff2    = (const float*)d_in[20];
  const float* W_dec    = (const float*)d_in[21];
  const float* b_dec    = (const float*)d_in[22];

  unsigned int* wsbase = (unsigned int*)d_ws;
  unsigned int* ctrs   = wsbase;           // 8 counters, 64B apart
  unsigned int* W      = wsbase + 128;     // packed weights

  hipMemsetAsync(d_ws, 0, 512, stream);

  auto launch_pack = [&](const float* src, unsigned int* dst, int K, int KPpad, int Dout) {
    int total = KPpad * Dout;
    int blocks = (total + 255) / 256;
    pack_wg_kernel<<<blocks, 256, 0, stream>>>(src, dst, K, KPpad, Dout);
  };

  launch_pack(W_ode, W + OFF_ODE, 512,  256, 512);
  launch_pack(W_kv,  W + OFF_KV,  552,  280, 1032);
  launch_pack(W_in,  W + OFF_IN,  40,   24,  512);
  launch_pack(W_q,   W + OFF_Q,   512,  256, 512);
  launch_pack(W_out, W + OFF_OUT, 512,  256, 512);
  launch_pack(W_ff1, W + OFF_F1,  512,  256, 2048);
  launch_pack(W_ff2, W + OFF_F2,  2048, 1024, 512);
  launch_pack(W_dec, W + OFF_DEC, 512,  256, 32);

  fwp_main<<<NS, 1024, 0, stream>>>(
      states, actions, tsteps,
      b_ode, b_in, ln_in_g, ln_in_b, b_q, b_kv, b_out, ln_ff_g, ln_ff_b,
      b_ff1, b_ff2, b_dec,
      W + OFF_ODE, W + OFF_KV, W + OFF_IN, W + OFF_Q,
      W + OFF_OUT, W + OFF_F1, W + OFF_F2, W + OFF_DEC,
      ctrs, (float*)d_out);
}